// Round 1
// baseline (345.879 us; speedup 1.0000x reference)
//
#include <hip/hip_runtime.h>

#define T_FRAMES 2400
#define V 25
#define C 128
#define VC 3200          // V*C
#define NB 3
#define GN_EPS 1e-5f
#define MAXDEG 16

// ---------------------------------------------------------------- adjacency
__global__ __launch_bounds__(256) void k_zero_deg(int* __restrict__ deg) {
    int i = blockIdx.x * 256 + threadIdx.x;
    if (i < T_FRAMES) deg[i] = 0;
}

__global__ __launch_bounds__(256) void k_scatter(
        const int* __restrict__ eidx, const float* __restrict__ ew, int E,
        int* __restrict__ deg, int* __restrict__ adjsrc, float* __restrict__ adjw) {
    int e = blockIdx.x * 256 + threadIdx.x;
    if (e >= E) return;
    int s = eidx[e];          // row 0: src
    int d = eidx[E + e];      // row 1: dst
    int slot = atomicAdd(&deg[d], 1);
    if (slot < MAXDEG) {
        adjsrc[d * MAXDEG + slot] = s;
        adjw  [d * MAXDEG + slot] = ew[e];
    }
}

// ------------------------------------------- spatial GCN + GroupNorm + ReLU
// One block per frame t.
// Phase 1: y[v][i*128+d] = sum_c x[t,v,c] * Ws[i,c,d]      (in LDS)
// Phase 2: h[u][d] = sum_{i,v} Aeff[i,u,v] * y[v][i*128+d] + sum_i bs[i,d]
// Phase 3: single-group GroupNorm over 3200 elems + affine + ReLU -> h_out
__global__ __launch_bounds__(256) void k_spatial(
        const float* __restrict__ x, const float* __restrict__ A,
        const float* __restrict__ EI, const float* __restrict__ Ws,
        const float* __restrict__ bs, const float* __restrict__ gamma,
        const float* __restrict__ beta, float* __restrict__ h_out)
{
    __shared__ float xt[V * C];            // 3200 floats
    __shared__ float aeff[NB * V * V];     // 1875 floats
    __shared__ float ybuf[V * NB * C];     // 9600 floats
    __shared__ float redS[4], redQ[4], bcast[2];

    const int t = blockIdx.x;
    const int tid = threadIdx.x;

    const float* xg = x + (size_t)t * VC;
    for (int i = tid; i < VC; i += 256) xt[i] = xg[i];
    for (int i = tid; i < NB * V * V; i += 256) aeff[i] = A[i] * EI[i];
    __syncthreads();

    // ---- Phase 1: per-frame GEMM [25 x 128] @ [128 x 384], 5x8 thread tile
    if (tid < 240) {
        const int gv = tid / 48;           // 0..4  -> rows v0..v0+4
        const int gn = tid % 48;           // 0..47 -> cols n0..n0+7 (n = i*128+d)
        const int v0 = gv * 5;
        const int n0 = gn * 8;
        const int ib = n0 >> 7;            // branch (8 | 128, so uniform over b)
        const int d0 = n0 & 127;
        const float4* __restrict__ wp = (const float4*)(Ws + ib * C * C + d0);
        float acc[5][8];
        #pragma unroll
        for (int a = 0; a < 5; a++)
            #pragma unroll
            for (int b = 0; b < 8; b++) acc[a][b] = 0.f;
        for (int c = 0; c < C; c++) {
            float xv[5];
            #pragma unroll
            for (int a = 0; a < 5; a++) xv[a] = xt[(v0 + a) * C + c];
            const float4 w0 = wp[c * 32];
            const float4 w1 = wp[c * 32 + 1];
            const float wn[8] = {w0.x, w0.y, w0.z, w0.w, w1.x, w1.y, w1.z, w1.w};
            #pragma unroll
            for (int a = 0; a < 5; a++)
                #pragma unroll
                for (int b = 0; b < 8; b++) acc[a][b] = fmaf(xv[a], wn[b], acc[a][b]);
        }
        #pragma unroll
        for (int a = 0; a < 5; a++)
            #pragma unroll
            for (int b = 0; b < 8; b++) ybuf[(v0 + a) * (NB * C) + n0 + b] = acc[a][b];
    }
    __syncthreads();

    // ---- Phase 2: adjacency mix. d = lane-contiguous, 13/12 u's per thread.
    const int d  = tid & 127;
    const int ug = tid >> 7;
    const int ub = ug ? 13 : 0;
    const int nu = ug ? 12 : 13;
    float hv[13];
    {
        const float bsum = bs[d] + bs[C + d] + bs[2 * C + d];
        #pragma unroll
        for (int j = 0; j < 13; j++) hv[j] = bsum;
    }
    for (int i = 0; i < NB; i++) {
        #pragma unroll 5
        for (int v = 0; v < V; v++) {
            const float y = ybuf[v * (NB * C) + i * C + d];
            const float* ae = &aeff[i * V * V + v];
            #pragma unroll
            for (int j = 0; j < 13; j++) {
                int u = ub + j; u = (u < V) ? u : (V - 1);   // clamp (garbage lane unused)
                hv[j] = fmaf(ae[u * V], y, hv[j]);
            }
        }
    }

    // ---- Phase 3: GroupNorm stats over the whole frame (3200 vals)
    float s = 0.f, q = 0.f;
    #pragma unroll
    for (int j = 0; j < 13; j++) if (j < nu) { s += hv[j]; q = fmaf(hv[j], hv[j], q); }
    #pragma unroll
    for (int off = 32; off > 0; off >>= 1) {
        s += __shfl_down(s, off);
        q += __shfl_down(q, off);
    }
    const int wid = tid >> 6;
    if ((tid & 63) == 0) { redS[wid] = s; redQ[wid] = q; }
    __syncthreads();
    if (tid == 0) {
        float S = redS[0] + redS[1] + redS[2] + redS[3];
        float Q = redQ[0] + redQ[1] + redQ[2] + redQ[3];
        float mu  = S / (float)VC;
        float var = Q / (float)VC - mu * mu;
        bcast[0] = mu;
        bcast[1] = rsqrtf(var + GN_EPS);
    }
    __syncthreads();
    const float mu = bcast[0], rs = bcast[1];
    float* ho = h_out + (size_t)t * VC;
    #pragma unroll
    for (int j = 0; j < 13; j++) {
        if (j < nu) {
            const int idx = (ub + j) * C + d;
            float val = (hv[j] - mu) * rs * gamma[idx] + beta[idx];
            ho[idx] = val > 0.f ? val : 0.f;
        }
    }
}

// -------------------------------- temporal gather-sum + GEMM + bias + ReLU
// out[t] = relu( (sum_{e: dst=t} ew_e * h[src_e]) @ Wt + bt )
// Block = 4 frames = 100 rows of [.,128] @ Wt[128,128].
#define K3F 4
#define K3R (K3F * V)     // 100 rows
#define ALS 132           // padded LDS stride (kills 4-way bank conflict)

__global__ __launch_bounds__(320) void k_temporal(
        const float* __restrict__ h, const int* __restrict__ deg,
        const int* __restrict__ adjsrc, const float* __restrict__ adjw,
        const float* __restrict__ Wt, const float* __restrict__ bt,
        float* __restrict__ out)
{
    __shared__ float AL[K3R * ALS];         // 13200 floats = 52.8 KB
    __shared__ int   s_src[K3F * MAXDEG];
    __shared__ float s_w[K3F * MAXDEG];
    __shared__ int   s_deg[K3F];

    const int tid = threadIdx.x;
    const int t0 = blockIdx.x * K3F;

    if (tid < K3F) s_deg[tid] = min(deg[t0 + tid], MAXDEG);
    if (tid >= 64 && tid < 64 + K3F * MAXDEG) {
        int i = tid - 64;
        int tf = i >> 4;
        s_src[i] = adjsrc[(t0 + tf) * MAXDEG + (i & 15)];
        s_w[i]   = adjw  [(t0 + tf) * MAXDEG + (i & 15)];
    }
    __syncthreads();

    // stage temporally-summed rows into LDS
    for (int i = tid; i < K3R * C; i += 320) {
        const int rl = i >> 7;
        const int c  = i & 127;
        const int tf = rl / V;
        const int u  = rl - tf * V;
        const int dg = s_deg[tf];
        float acc = 0.f;
        for (int e = 0; e < dg; e++) {
            acc = fmaf(s_w[tf * MAXDEG + e],
                       h[(size_t)s_src[tf * MAXDEG + e] * VC + u * C + c], acc);
        }
        AL[rl * ALS + c] = acc;
    }
    __syncthreads();

    // GEMM: 100x128 tile, 5x8 per thread, 320 threads
    const int gr = tid >> 4;      // 0..19 -> rows gr*5..+4
    const int gc = tid & 15;      // 0..15 -> cols gc*8..+7
    const int d0 = gc * 8;
    const float4* __restrict__ wp = (const float4*)(Wt + d0);
    float acc[5][8];
    #pragma unroll
    for (int a = 0; a < 5; a++)
        #pragma unroll
        for (int b = 0; b < 8; b++) acc[a][b] = 0.f;
    for (int c = 0; c < C; c++) {
        float av[5];
        #pragma unroll
        for (int a = 0; a < 5; a++) av[a] = AL[(gr * 5 + a) * ALS + c];
        const float4 w0 = wp[c * 32];
        const float4 w1 = wp[c * 32 + 1];
        const float wn[8] = {w0.x, w0.y, w0.z, w0.w, w1.x, w1.y, w1.z, w1.w};
        #pragma unroll
        for (int a = 0; a < 5; a++)
            #pragma unroll
            for (int b = 0; b < 8; b++) acc[a][b] = fmaf(av[a], wn[b], acc[a][b]);
    }

    const float4 b0 = *(const float4*)(bt + d0);
    const float4 b1 = *(const float4*)(bt + d0 + 4);
    const float btv[8] = {b0.x, b0.y, b0.z, b0.w, b1.x, b1.y, b1.z, b1.w};
    #pragma unroll
    for (int a = 0; a < 5; a++) {
        const int r = gr * 5 + a;
        float4 o0, o1;
        o0.x = fmaxf(acc[a][0] + btv[0], 0.f);
        o0.y = fmaxf(acc[a][1] + btv[1], 0.f);
        o0.z = fmaxf(acc[a][2] + btv[2], 0.f);
        o0.w = fmaxf(acc[a][3] + btv[3], 0.f);
        o1.x = fmaxf(acc[a][4] + btv[4], 0.f);
        o1.y = fmaxf(acc[a][5] + btv[5], 0.f);
        o1.z = fmaxf(acc[a][6] + btv[6], 0.f);
        o1.w = fmaxf(acc[a][7] + btv[7], 0.f);
        float* op = out + ((size_t)t0 * V + r) * C + d0;
        *(float4*)op = o0;
        *(float4*)(op + 4) = o1;
    }
}

// ---------------------------------------------------------------- launcher
extern "C" void kernel_launch(void* const* d_in, const int* in_sizes, int n_in,
                              void* d_out, int out_size, void* d_ws, size_t ws_size,
                              hipStream_t stream) {
    const float* x     = (const float*)d_in[0];
    const float* A     = (const float*)d_in[1];
    const float* EI    = (const float*)d_in[2];
    const float* Ws    = (const float*)d_in[3];
    const float* bs    = (const float*)d_in[4];
    const float* Wt    = (const float*)d_in[5];
    const float* bt    = (const float*)d_in[6];
    const float* gamma = (const float*)d_in[7];
    const float* beta  = (const float*)d_in[8];
    const float* ew    = (const float*)d_in[9];
    const int*   eidx  = (const int*)d_in[10];
    const int E = in_sizes[9];

    float* ws     = (float*)d_ws;
    float* h      = ws;                                  // 7,680,000 floats
    int*   deg    = (int*)(ws + (size_t)T_FRAMES * VC);  // 2400 ints
    int*   adjsrc = deg + T_FRAMES;                      // 2400*16 ints
    float* adjw   = (float*)(adjsrc + T_FRAMES * MAXDEG);

    float* out = (float*)d_out;

    k_zero_deg<<<(T_FRAMES + 255) / 256, 256, 0, stream>>>(deg);
    k_scatter<<<(E + 255) / 256, 256, 0, stream>>>(eidx, ew, E, deg, adjsrc, adjw);
    k_spatial<<<T_FRAMES, 256, 0, stream>>>(x, A, EI, Ws, bs, gamma, beta, h);
    k_temporal<<<T_FRAMES / K3F, 320, 0, stream>>>(h, deg, adjsrc, adjw, Wt, bt, out);
}

// Round 2
// 204.261 us; speedup vs baseline: 1.6933x; 1.6933x over previous
//
#include <hip/hip_runtime.h>

#define T_FRAMES 2400
#define V 25
#define C 128
#define VC 3200          // V*C
#define NB 3
#define GN_EPS 1e-5f
#define MAXDEG 16
#define KS 384           // spatial GEMM K = 3*C
#define XA_STRIDE 392    // padded bf16 row stride (392*2B = 49*16B, bank-shift 4)
#define AGG_STRIDE 136   // padded bf16 row stride (136*2B = 17*16B, bank-shift 4)

typedef __attribute__((ext_vector_type(8))) short short8;   // 8 bf16 (4 VGPR)
typedef __attribute__((ext_vector_type(4))) float floatx4;  // MFMA accum
typedef unsigned short u16;
typedef unsigned int u32;

__device__ __forceinline__ u16 f2bf(float f) {
    u32 u = __builtin_bit_cast(u32, f);
    u += 0x7FFFu + ((u >> 16) & 1u);          // RNE
    return (u16)(u >> 16);
}
__device__ __forceinline__ float bf2f(u16 h) {
    u32 u = ((u32)h) << 16;
    return __builtin_bit_cast(float, u);
}

// ------------------------------------------------------------------ prep
// Swizzle Ws/Wt to bf16 [k>>3][n][k&7] so B-frags are contiguous 16B;
// Aeff = A*EI; bsum = sum_i bs; zero deg.
__global__ __launch_bounds__(256) void k_prep(
        const float* __restrict__ Ws, const float* __restrict__ Wt,
        const float* __restrict__ A, const float* __restrict__ EI,
        const float* __restrict__ bs,
        u16* __restrict__ Wsw, u16* __restrict__ Wtsw,
        float* __restrict__ aeff, float* __restrict__ bsum, int* __restrict__ deg)
{
    const int idx = blockIdx.x * 256 + threadIdx.x;
    if (idx < KS * C) {
        const int j = idx & 7, n = (idx >> 3) & 127, kg = idx >> 10;
        const int k = kg * 8 + j;
        Wsw[idx] = f2bf(Ws[k * C + n]);
    }
    if (idx < C * C) {
        const int j = idx & 7, n = (idx >> 3) & 127, kg = idx >> 10;
        const int k = kg * 8 + j;
        Wtsw[idx] = f2bf(Wt[k * C + n]);
    }
    if (idx < NB * V * V) aeff[idx] = A[idx] * EI[idx];
    if (idx < C) bsum[idx] = bs[idx] + bs[C + idx] + bs[2 * C + idx];
    if (idx < T_FRAMES) deg[idx] = 0;
}

__global__ __launch_bounds__(256) void k_scatter(
        const int* __restrict__ eidx, const float* __restrict__ ew, int E,
        int* __restrict__ deg, int* __restrict__ adjsrc, float* __restrict__ adjw) {
    const int e = blockIdx.x * 256 + threadIdx.x;
    if (e >= E) return;
    const int s = eidx[e];
    const int d = eidx[E + e];
    const int slot = atomicAdd(&deg[d], 1);
    if (slot < MAXDEG) {
        adjsrc[d * MAXDEG + slot] = s;
        adjw  [d * MAXDEG + slot] = ew[e];
    }
}

// ---------------------------------------------- spatial: mix + MFMA + GN
// Per frame: xa[u][(i,c)] = sum_v aeff[i,u,v]*x[t,v,c]  (VALU, bf16 to LDS)
//            h = xa[25x384] @ Ws'[384x128]              (MFMA, B-frags resident)
//            h += bsum; GroupNorm(3200); ReLU; store bf16.
__global__ __launch_bounds__(512, 4) void k_spatial(
        const float* __restrict__ x, const float* __restrict__ aeff_g,
        const u16* __restrict__ Wsw, const float* __restrict__ bsum_g,
        const float* __restrict__ gamma_g, const float* __restrict__ beta_g,
        u16* __restrict__ h_g)
{
    __shared__ float xt[VC];                  // 12.8 KB
    __shared__ u16   xa[32 * XA_STRIDE];      // 25.1 KB
    __shared__ float aeff[NB * V * V];        // 7.5 KB
    __shared__ float gbuf[VC];                // 12.8 KB
    __shared__ float bbuf[VC];                // 12.8 KB
    __shared__ float redS[8], redQ[8], bcast[2];

    const int tid = threadIdx.x;
    const int w   = tid >> 6;        // wave 0..7 -> n-tile
    const int l   = tid & 63;
    const int q   = l >> 4;          // quad
    const int ln  = l & 15;
    const int col = w * 16 + ln;     // output column this lane owns

    // one-time block staging
    for (int i = tid; i < NB * V * V; i += 512) aeff[i] = aeff_g[i];
    for (int i = tid; i < VC; i += 512) { gbuf[i] = gamma_g[i]; bbuf[i] = beta_g[i]; }
    for (int i = tid; i < 7 * XA_STRIDE; i += 512) xa[25 * XA_STRIDE + i] = 0; // pad rows

    // resident B-fragments: B[k][n], lane holds k = s*32+q*8+j, n = col
    short8 bfr[12];
    #pragma unroll
    for (int s = 0; s < 12; s++)
        bfr[s] = *reinterpret_cast<const short8*>(Wsw + ((s * 4 + q) * C + col) * 8);
    const float bsv = bsum_g[col];

    // xa-compute mapping: 480 active threads: branch xi, u-group xug(5 rows), 4 cols
    const bool xact = tid < 480;
    const int xi  = tid / 160;
    const int xr  = tid % 160;
    const int xug = xr >> 5;
    const int xc0 = (xr & 31) * 4;

    for (int t = blockIdx.x; t < T_FRAMES; t += gridDim.x) {
        __syncthreads();  // (A) prev-iter readers done
        const float4* xg = (const float4*)(x + (size_t)t * VC);
        for (int i = tid; i < VC / 4; i += 512) ((float4*)xt)[i] = xg[i];
        __syncthreads();  // (B) xt ready

        if (xact) {
            float a4[5][4];
            #pragma unroll
            for (int uu = 0; uu < 5; uu++)
                #pragma unroll
                for (int cc = 0; cc < 4; cc++) a4[uu][cc] = 0.f;
            const float* ap = aeff + xi * V * V + (xug * 5) * V;
            #pragma unroll 5
            for (int v = 0; v < V; v++) {
                const float4 xv = *(const float4*)&xt[v * C + xc0];
                #pragma unroll
                for (int uu = 0; uu < 5; uu++) {
                    const float ae = ap[uu * V + v];
                    a4[uu][0] = fmaf(ae, xv.x, a4[uu][0]);
                    a4[uu][1] = fmaf(ae, xv.y, a4[uu][1]);
                    a4[uu][2] = fmaf(ae, xv.z, a4[uu][2]);
                    a4[uu][3] = fmaf(ae, xv.w, a4[uu][3]);
                }
            }
            #pragma unroll
            for (int uu = 0; uu < 5; uu++) {
                const int row = xug * 5 + uu;
                uint2 pk;
                pk.x = (u32)f2bf(a4[uu][0]) | ((u32)f2bf(a4[uu][1]) << 16);
                pk.y = (u32)f2bf(a4[uu][2]) | ((u32)f2bf(a4[uu][3]) << 16);
                *(uint2*)&xa[row * XA_STRIDE + xi * C + xc0] = pk;
            }
        }
        __syncthreads();  // (C) xa ready

        // MFMA: rows 0-15 (acc0), rows 16-31 (acc1, rows>=25 are zero pad)
        floatx4 acc0 = {0.f, 0.f, 0.f, 0.f}, acc1 = {0.f, 0.f, 0.f, 0.f};
        #pragma unroll
        for (int s = 0; s < 12; s++) {
            const short8 a0 = *reinterpret_cast<const short8*>(&xa[ln * XA_STRIDE + s * 32 + q * 8]);
            const short8 a1 = *reinterpret_cast<const short8*>(&xa[(16 + ln) * XA_STRIDE + s * 32 + q * 8]);
            acc0 = __builtin_amdgcn_mfma_f32_16x16x32_bf16(a0, bfr[s], acc0, 0, 0, 0);
            acc1 = __builtin_amdgcn_mfma_f32_16x16x32_bf16(a1, bfr[s], acc1, 0, 0, 0);
        }

        // bias + GN stats (mask pad rows)
        float s_p = 0.f, q_p = 0.f;
        #pragma unroll
        for (int r = 0; r < 4; r++) {
            acc0[r] += bsv;
            s_p += acc0[r]; q_p = fmaf(acc0[r], acc0[r], q_p);
        }
        #pragma unroll
        for (int r = 0; r < 4; r++) {
            acc1[r] += bsv;
            if (q * 4 + r < 9) { s_p += acc1[r]; q_p = fmaf(acc1[r], acc1[r], q_p); }
        }
        #pragma unroll
        for (int off = 32; off; off >>= 1) {
            s_p += __shfl_down(s_p, off);
            q_p += __shfl_down(q_p, off);
        }
        if (l == 0) { redS[w] = s_p; redQ[w] = q_p; }
        __syncthreads();  // (D)
        if (tid == 0) {
            float S = 0.f, Q = 0.f;
            #pragma unroll
            for (int i = 0; i < 8; i++) { S += redS[i]; Q += redQ[i]; }
            const float mu  = S / (float)VC;
            const float var = Q / (float)VC - mu * mu;
            bcast[0] = mu;
            bcast[1] = rsqrtf(fmaxf(var, 0.f) + GN_EPS);
        }
        __syncthreads();  // (E)
        const float mu = bcast[0], rs = bcast[1];
        u16* hp = h_g + (size_t)t * VC;
        #pragma unroll
        for (int r = 0; r < 4; r++) {
            const int idx = (q * 4 + r) * C + col;
            const float v = (acc0[r] - mu) * rs * gbuf[idx] + bbuf[idx];
            hp[idx] = f2bf(v > 0.f ? v : 0.f);
        }
        #pragma unroll
        for (int r = 0; r < 4; r++) {
            const int row = 16 + q * 4 + r;
            if (row < V) {
                const int idx = row * C + col;
                const float v = (acc1[r] - mu) * rs * gbuf[idx] + bbuf[idx];
                hp[idx] = f2bf(v > 0.f ? v : 0.f);
            }
        }
    }
}

// ------------------------------- temporal: gather-sum + MFMA + bias + ReLU
__global__ __launch_bounds__(512, 4) void k_temporal(
        const u16* __restrict__ h, const int* __restrict__ deg,
        const int* __restrict__ adjsrc, const float* __restrict__ adjw,
        const u16* __restrict__ Wtsw, const float* __restrict__ bt,
        float* __restrict__ out)
{
    __shared__ u16   agg[32 * AGG_STRIDE];   // 8.7 KB
    __shared__ int   s_src[MAXDEG];
    __shared__ float s_w[MAXDEG];
    __shared__ int   s_deg;

    const int tid = threadIdx.x;
    const int w   = tid >> 6;
    const int l   = tid & 63;
    const int q   = l >> 4;
    const int ln  = l & 15;
    const int col = w * 16 + ln;

    for (int i = tid; i < 7 * AGG_STRIDE; i += 512) agg[25 * AGG_STRIDE + i] = 0;

    short8 bfr[4];
    #pragma unroll
    for (int s = 0; s < 4; s++)
        bfr[s] = *reinterpret_cast<const short8*>(Wtsw + ((s * 4 + q) * C + col) * 8);
    const float btv = bt[col];

    for (int t = blockIdx.x; t < T_FRAMES; t += gridDim.x) {
        __syncthreads();  // prev readers done
        if (tid < MAXDEG) { s_src[tid] = adjsrc[t * MAXDEG + tid]; s_w[tid] = adjw[t * MAXDEG + tid]; }
        if (tid == MAXDEG) s_deg = min(deg[t], MAXDEG);
        __syncthreads();
        const int dg = s_deg;
        for (int o = tid; o < VC; o += 512) {
            float acc = 0.f;
            for (int e = 0; e < dg; e++)
                acc = fmaf(s_w[e], bf2f(h[(size_t)s_src[e] * VC + o]), acc);
            agg[(o >> 7) * AGG_STRIDE + (o & 127)] = f2bf(acc);
        }
        __syncthreads();  // agg ready

        floatx4 acc0 = {0.f, 0.f, 0.f, 0.f}, acc1 = {0.f, 0.f, 0.f, 0.f};
        #pragma unroll
        for (int s = 0; s < 4; s++) {
            const short8 a0 = *reinterpret_cast<const short8*>(&agg[ln * AGG_STRIDE + s * 32 + q * 8]);
            const short8 a1 = *reinterpret_cast<const short8*>(&agg[(16 + ln) * AGG_STRIDE + s * 32 + q * 8]);
            acc0 = __builtin_amdgcn_mfma_f32_16x16x32_bf16(a0, bfr[s], acc0, 0, 0, 0);
            acc1 = __builtin_amdgcn_mfma_f32_16x16x32_bf16(a1, bfr[s], acc1, 0, 0, 0);
        }
        float* op = out + (size_t)t * VC;
        #pragma unroll
        for (int r = 0; r < 4; r++) {
            const float v = acc0[r] + btv;
            op[(q * 4 + r) * C + col] = v > 0.f ? v : 0.f;
        }
        #pragma unroll
        for (int r = 0; r < 4; r++) {
            const int row = 16 + q * 4 + r;
            if (row < V) {
                const float v = acc1[r] + btv;
                op[row * C + col] = v > 0.f ? v : 0.f;
            }
        }
    }
}

// ---------------------------------------------------------------- launcher
extern "C" void kernel_launch(void* const* d_in, const int* in_sizes, int n_in,
                              void* d_out, int out_size, void* d_ws, size_t ws_size,
                              hipStream_t stream) {
    const float* x     = (const float*)d_in[0];
    const float* A     = (const float*)d_in[1];
    const float* EI    = (const float*)d_in[2];
    const float* Ws    = (const float*)d_in[3];
    const float* bs    = (const float*)d_in[4];
    const float* Wt    = (const float*)d_in[5];
    const float* bt    = (const float*)d_in[6];
    const float* gamma = (const float*)d_in[7];
    const float* beta  = (const float*)d_in[8];
    const float* ew    = (const float*)d_in[9];
    const int*   eidx  = (const int*)d_in[10];
    const int E = in_sizes[9];

    char* ws = (char*)d_ws;
    u16*   h      = (u16*)(ws);                          // 15,360,000 B
    u16*   Wsw    = (u16*)(ws + 15360000);               // 98,304 B
    u16*   Wtsw   = (u16*)(ws + 15458304);               // 32,768 B
    float* aeff   = (float*)(ws + 15491072);             // 7,500 B
    float* bsum   = (float*)(ws + 15498576);             // 512 B
    int*   deg    = (int*)(ws + 15499088);               // 9,600 B
    int*   adjsrc = (int*)(ws + 15508688);               // 153,600 B
    float* adjw   = (float*)(ws + 15662288);             // 153,600 B

    float* out = (float*)d_out;

    k_prep<<<(KS * C + 255) / 256, 256, 0, stream>>>(Ws, Wt, A, EI, bs, Wsw, Wtsw, aeff, bsum, deg);
    k_scatter<<<(E + 255) / 256, 256, 0, stream>>>(eidx, ew, E, deg, adjsrc, adjw);
    k_spatial<<<512, 512, 0, stream>>>(x, aeff, Wsw, bsum, gamma, beta, h);
    k_temporal<<<1024, 512, 0, stream>>>(h, deg, adjsrc, adjw, Wtsw, bt, out);
}

// Round 3
// 176.949 us; speedup vs baseline: 1.9547x; 1.1543x over previous
//
#include <hip/hip_runtime.h>

#define T_FRAMES 2400
#define V 25
#define C 128
#define VC 3200          // V*C
#define NB 3
#define GN_EPS 1e-5f
#define MAXDEG 16
#define KS 384           // spatial GEMM K = 3*C
#define XA_STRIDE 392    // padded bf16 row stride (784B; 784 mod 128 = 16 -> conflict-free b128)
#define AGG_STRIDE 136   // padded bf16 row stride (272B; 272 mod 128 = 16 -> conflict-free b128)
#define FPB 4            // frames per block (both kernels)

typedef __attribute__((ext_vector_type(8))) short short8;   // 8 bf16 (4 VGPR)
typedef __attribute__((ext_vector_type(4))) float floatx4;  // MFMA accum
typedef unsigned short u16;
typedef unsigned int u32;

__device__ __forceinline__ u16 f2bf(float f) {
    u32 u = __builtin_bit_cast(u32, f);
    u += 0x7FFFu + ((u >> 16) & 1u);          // RNE
    return (u16)(u >> 16);
}
__device__ __forceinline__ float bf2f(u16 h) {
    u32 u = ((u32)h) << 16;
    return __builtin_bit_cast(float, u);
}

// ------------------------------------------------------------------ prep
__global__ __launch_bounds__(256) void k_prep(
        const float* __restrict__ Ws, const float* __restrict__ Wt,
        const float* __restrict__ A, const float* __restrict__ EI,
        const float* __restrict__ bs,
        u16* __restrict__ Wsw, u16* __restrict__ Wtsw,
        float* __restrict__ aeff, float* __restrict__ bsum, int* __restrict__ deg)
{
    const int idx = blockIdx.x * 256 + threadIdx.x;
    if (idx < KS * C) {
        const int j = idx & 7, n = (idx >> 3) & 127, kg = idx >> 10;
        const int k = kg * 8 + j;
        Wsw[idx] = f2bf(Ws[k * C + n]);
    }
    if (idx < C * C) {
        const int j = idx & 7, n = (idx >> 3) & 127, kg = idx >> 10;
        const int k = kg * 8 + j;
        Wtsw[idx] = f2bf(Wt[k * C + n]);
    }
    if (idx < NB * V * V) aeff[idx] = A[idx] * EI[idx];
    if (idx < C) bsum[idx] = bs[idx] + bs[C + idx] + bs[2 * C + idx];
    if (idx < T_FRAMES) deg[idx] = 0;
}

__global__ __launch_bounds__(256) void k_scatter(
        const int* __restrict__ eidx, const float* __restrict__ ew, int E,
        int* __restrict__ deg, int* __restrict__ adjsrc, float* __restrict__ adjw) {
    const int e = blockIdx.x * 256 + threadIdx.x;
    if (e >= E) return;
    const int s = eidx[e];
    const int d = eidx[E + e];
    const int slot = atomicAdd(&deg[d], 1);
    if (slot < MAXDEG) {
        adjsrc[d * MAXDEG + slot] = s;
        adjw  [d * MAXDEG + slot] = ew[e];
    }
}

// ---------------------------------------------- spatial: mix + MFMA + GN
// 600 blocks x 4 frames. Double-buffered xt, 3 barriers/frame.
__global__ __launch_bounds__(512, 4) void k_spatial(
        const float* __restrict__ x, const float* __restrict__ aeff_g,
        const u16* __restrict__ Wsw, const float* __restrict__ bsum_g,
        const float* __restrict__ gamma_g, const float* __restrict__ beta_g,
        u16* __restrict__ h_g)
{
    __shared__ float xt[2][VC];               // 25.6 KB
    __shared__ u16   xa[32 * XA_STRIDE];      // 25.1 KB
    __shared__ float aeff[NB * V * V];        // 7.5 KB
    __shared__ float redS[8], redQ[8];

    const int tid = threadIdx.x;
    const int w   = tid >> 6;        // wave 0..7 -> n-tile
    const int l   = tid & 63;
    const int q   = l >> 4;          // quad
    const int ln  = l & 15;
    const int col = w * 16 + ln;     // output column this lane owns

    const int t0 = blockIdx.x * FPB;

    // one-time block staging
    for (int i = tid; i < NB * V * V; i += 512) aeff[i] = aeff_g[i];
    for (int i = tid; i < 7 * XA_STRIDE; i += 512) xa[25 * XA_STRIDE + i] = 0; // pad rows

    // resident B-fragments: B[k][n], lane holds k = s*32+q*8+j, n = col
    short8 bfr[12];
    #pragma unroll
    for (int s = 0; s < 12; s++)
        bfr[s] = *reinterpret_cast<const short8*>(Wsw + ((s * 4 + q) * C + col) * 8);
    const float bsv = bsum_g[col];

    // xa-compute mapping: 480 active threads: branch xi, u-group xug(5 rows), 4 cols
    const bool xact = tid < 480;
    const int xi  = tid / 160;
    const int xr  = tid % 160;
    const int xug = xr >> 5;
    const int xc0 = (xr & 31) * 4;

    // prolog: stage x[t0] into xt[0]
    {
        const float4* xg = (const float4*)(x + (size_t)t0 * VC);
        float4* d = (float4*)&xt[0][0];
        d[tid] = xg[tid];
        if (tid < 288) d[tid + 512] = xg[tid + 512];
    }
    __syncthreads();

    for (int f = 0; f < FPB; f++) {
        const int t = t0 + f;
        const int cur = f & 1;

        // issue next frame's x loads early (latency hidden under mix)
        float4 p0, p1;
        if (f < FPB - 1) {
            const float4* xg = (const float4*)(x + (size_t)(t + 1) * VC);
            p0 = xg[tid];
            if (tid < 288) p1 = xg[tid + 512];
        }

        if (xact) {
            float a4[5][4];
            #pragma unroll
            for (int uu = 0; uu < 5; uu++)
                #pragma unroll
                for (int cc = 0; cc < 4; cc++) a4[uu][cc] = 0.f;
            const float* ap = aeff + xi * V * V + (xug * 5) * V;
            #pragma unroll 5
            for (int v = 0; v < V; v++) {
                const float4 xv = *(const float4*)&xt[cur][v * C + xc0];
                #pragma unroll
                for (int uu = 0; uu < 5; uu++) {
                    const float ae = ap[uu * V + v];
                    a4[uu][0] = fmaf(ae, xv.x, a4[uu][0]);
                    a4[uu][1] = fmaf(ae, xv.y, a4[uu][1]);
                    a4[uu][2] = fmaf(ae, xv.z, a4[uu][2]);
                    a4[uu][3] = fmaf(ae, xv.w, a4[uu][3]);
                }
            }
            #pragma unroll
            for (int uu = 0; uu < 5; uu++) {
                const int row = xug * 5 + uu;
                uint2 pk;
                pk.x = (u32)f2bf(a4[uu][0]) | ((u32)f2bf(a4[uu][1]) << 16);
                pk.y = (u32)f2bf(a4[uu][2]) | ((u32)f2bf(a4[uu][3]) << 16);
                *(uint2*)&xa[row * XA_STRIDE + xi * C + xc0] = pk;
            }
        }

        // park next x into the other buffer (nobody reads it until next iter)
        if (f < FPB - 1) {
            float4* d = (float4*)&xt[cur ^ 1][0];
            d[tid] = p0;
            if (tid < 288) d[tid + 512] = p1;
        }
        __syncthreads();  // xa ready (and xt[nxt] parked)

        // MFMA: rows 0-15 (acc0), rows 16-31 (acc1, rows>=25 zero pad)
        floatx4 acc0 = {0.f, 0.f, 0.f, 0.f}, acc1 = {0.f, 0.f, 0.f, 0.f};
        #pragma unroll
        for (int s = 0; s < 12; s++) {
            const short8 a0 = *reinterpret_cast<const short8*>(&xa[ln * XA_STRIDE + s * 32 + q * 8]);
            const short8 a1 = *reinterpret_cast<const short8*>(&xa[(16 + ln) * XA_STRIDE + s * 32 + q * 8]);
            acc0 = __builtin_amdgcn_mfma_f32_16x16x32_bf16(a0, bfr[s], acc0, 0, 0, 0);
            acc1 = __builtin_amdgcn_mfma_f32_16x16x32_bf16(a1, bfr[s], acc1, 0, 0, 0);
        }

        // bias + GN stats (mask pad rows)
        float s_p = 0.f, q_p = 0.f;
        #pragma unroll
        for (int r = 0; r < 4; r++) {
            acc0[r] += bsv;
            s_p += acc0[r]; q_p = fmaf(acc0[r], acc0[r], q_p);
        }
        #pragma unroll
        for (int r = 0; r < 4; r++) {
            acc1[r] += bsv;
            if (q * 4 + r < 9) { s_p += acc1[r]; q_p = fmaf(acc1[r], acc1[r], q_p); }
        }
        #pragma unroll
        for (int off = 32; off; off >>= 1) {
            s_p += __shfl_down(s_p, off);
            q_p += __shfl_down(q_p, off);
        }
        if (l == 0) { redS[w] = s_p; redQ[w] = q_p; }
        __syncthreads();  // partials ready; also guarantees all xa reads done
        float S = 0.f, Q = 0.f;
        #pragma unroll
        for (int i = 0; i < 8; i++) { S += redS[i]; Q += redQ[i]; }
        const float mu  = S / (float)VC;
        const float var = Q / (float)VC - mu * mu;
        const float rs  = rsqrtf(fmaxf(var, 0.f) + GN_EPS);

        u16* hp = h_g + (size_t)t * VC;
        #pragma unroll
        for (int r = 0; r < 4; r++) {
            const int idx = (q * 4 + r) * C + col;
            const float v = (acc0[r] - mu) * rs * gamma_g[idx] + beta_g[idx];
            hp[idx] = f2bf(v > 0.f ? v : 0.f);
        }
        #pragma unroll
        for (int r = 0; r < 4; r++) {
            const int row = 16 + q * 4 + r;
            if (row < V) {
                const int idx = row * C + col;
                const float v = (acc1[r] - mu) * rs * gamma_g[idx] + beta_g[idx];
                hp[idx] = f2bf(v > 0.f ? v : 0.f);
            }
        }
        __syncthreads();  // redS/redQ reads done before next iter overwrites
    }
}

// ------------------------------- temporal: gather-sum + MFMA + bias + ReLU
// 600 blocks x 4 consecutive frames. Vectorized short8 gather.
__global__ __launch_bounds__(512, 4) void k_temporal(
        const u16* __restrict__ h, const int* __restrict__ deg,
        const int* __restrict__ adjsrc, const float* __restrict__ adjw,
        const u16* __restrict__ Wtsw, const float* __restrict__ bt,
        float* __restrict__ out)
{
    __shared__ u16   agg[FPB * 32 * AGG_STRIDE];   // 34.8 KB
    __shared__ int   s_src[FPB * MAXDEG];
    __shared__ float s_w[FPB * MAXDEG];
    __shared__ int   s_deg[FPB];

    const int tid = threadIdx.x;
    const int w   = tid >> 6;
    const int l   = tid & 63;
    const int q   = l >> 4;
    const int ln  = l & 15;
    const int col = w * 16 + ln;

    const int t0 = blockIdx.x * FPB;

    // stage adjacency + zero pad rows
    if (tid < FPB * MAXDEG) {
        const int tf = tid >> 4;
        s_src[tid] = adjsrc[(t0 + tf) * MAXDEG + (tid & 15)];
        s_w[tid]   = adjw  [(t0 + tf) * MAXDEG + (tid & 15)];
    }
    if (tid >= 64 && tid < 64 + FPB) s_deg[tid - 64] = min(deg[t0 + tid - 64], MAXDEG);
    for (int i = tid; i < FPB * 7 * AGG_STRIDE; i += 512)
        agg[FPB == 1 ? 25 * AGG_STRIDE + i
                     : (i / (7 * AGG_STRIDE)) * 32 * AGG_STRIDE + 25 * AGG_STRIDE + (i % (7 * AGG_STRIDE))] = 0;

    // resident B-fragments
    short8 bfr[4];
    #pragma unroll
    for (int s = 0; s < 4; s++)
        bfr[s] = *reinterpret_cast<const short8*>(Wtsw + ((s * 4 + q) * C + col) * 8);
    const float btv = bt[col];
    __syncthreads();

    // vectorized gather: FPB*V*16 = 1600 short8 units
    for (int u = tid; u < FPB * V * 16; u += 512) {
        const int f  = u / (V * 16);
        const int rc = u - f * (V * 16);
        const int row = rc >> 4;
        const int c8  = rc & 15;
        const u16* hp = h + row * C + c8 * 8;
        const int dg = s_deg[f];
        float a8[8] = {0.f, 0.f, 0.f, 0.f, 0.f, 0.f, 0.f, 0.f};
        for (int e = 0; e < dg; e++) {
            const short8 hv = *reinterpret_cast<const short8*>(hp + (size_t)s_src[f * MAXDEG + e] * VC);
            const float wv = s_w[f * MAXDEG + e];
            #pragma unroll
            for (int i = 0; i < 8; i++) a8[i] = fmaf(wv, bf2f((u16)hv[i]), a8[i]);
        }
        u32 pk[4];
        #pragma unroll
        for (int i = 0; i < 4; i++)
            pk[i] = (u32)f2bf(a8[2 * i]) | ((u32)f2bf(a8[2 * i + 1]) << 16);
        *reinterpret_cast<uint4*>(&agg[(f * 32 + row) * AGG_STRIDE + c8 * 8]) =
            *reinterpret_cast<uint4*>(pk);
    }
    __syncthreads();

    #pragma unroll
    for (int f = 0; f < FPB; f++) {
        floatx4 acc0 = {0.f, 0.f, 0.f, 0.f}, acc1 = {0.f, 0.f, 0.f, 0.f};
        const u16* ab = &agg[f * 32 * AGG_STRIDE];
        #pragma unroll
        for (int s = 0; s < 4; s++) {
            const short8 a0 = *reinterpret_cast<const short8*>(&ab[ln * AGG_STRIDE + s * 32 + q * 8]);
            const short8 a1 = *reinterpret_cast<const short8*>(&ab[(16 + ln) * AGG_STRIDE + s * 32 + q * 8]);
            acc0 = __builtin_amdgcn_mfma_f32_16x16x32_bf16(a0, bfr[s], acc0, 0, 0, 0);
            acc1 = __builtin_amdgcn_mfma_f32_16x16x32_bf16(a1, bfr[s], acc1, 0, 0, 0);
        }
        float* op = out + (size_t)(t0 + f) * VC;
        #pragma unroll
        for (int r = 0; r < 4; r++) {
            const float v = acc0[r] + btv;
            op[(q * 4 + r) * C + col] = v > 0.f ? v : 0.f;
        }
        #pragma unroll
        for (int r = 0; r < 4; r++) {
            const int row = 16 + q * 4 + r;
            if (row < V) {
                const float v = acc1[r] + btv;
                op[row * C + col] = v > 0.f ? v : 0.f;
            }
        }
    }
}

// ---------------------------------------------------------------- launcher
extern "C" void kernel_launch(void* const* d_in, const int* in_sizes, int n_in,
                              void* d_out, int out_size, void* d_ws, size_t ws_size,
                              hipStream_t stream) {
    const float* x     = (const float*)d_in[0];
    const float* A     = (const float*)d_in[1];
    const float* EI    = (const float*)d_in[2];
    const float* Ws    = (const float*)d_in[3];
    const float* bs    = (const float*)d_in[4];
    const float* Wt    = (const float*)d_in[5];
    const float* bt    = (const float*)d_in[6];
    const float* gamma = (const float*)d_in[7];
    const float* beta  = (const float*)d_in[8];
    const float* ew    = (const float*)d_in[9];
    const int*   eidx  = (const int*)d_in[10];
    const int E = in_sizes[9];

    char* ws = (char*)d_ws;
    u16*   h      = (u16*)(ws);                          // 15,360,000 B
    u16*   Wsw    = (u16*)(ws + 15360000);               // 98,304 B
    u16*   Wtsw   = (u16*)(ws + 15458304);               // 32,768 B
    float* aeff   = (float*)(ws + 15491072);             // 7,500 B
    float* bsum   = (float*)(ws + 15498576);             // 512 B
    int*   deg    = (int*)(ws + 15499088);               // 9,600 B
    int*   adjsrc = (int*)(ws + 15508688);               // 153,600 B
    float* adjw   = (float*)(ws + 15662288);             // 153,600 B

    float* out = (float*)d_out;

    k_prep<<<(KS * C + 255) / 256, 256, 0, stream>>>(Ws, Wt, A, EI, bs, Wsw, Wtsw, aeff, bsum, deg);
    k_scatter<<<(E + 255) / 256, 256, 0, stream>>>(eidx, ew, E, deg, adjsrc, adjw);
    k_spatial<<<T_FRAMES / FPB, 512, 0, stream>>>(x, aeff, Wsw, bsum, gamma, beta, h);
    k_temporal<<<T_FRAMES / FPB, 512, 0, stream>>>(h, deg, adjsrc, adjw, Wtsw, bt, out);
}